// Round 2
// baseline (85.487 us; speedup 1.0000x reference)
//
#include <hip/hip_runtime.h>
#include <stdint.h>
#include <stddef.h>

typedef int   v4i __attribute__((ext_vector_type(4)));
typedef float v4f __attribute__((ext_vector_type(4)));

#define BM 128
#define BN 128
#define BKB 128          // K-bytes (int8 elems) staged per tile
#define M_DIM 32768
#define N_DIM 1024
#define K_DIM 1024

typedef const __attribute__((address_space(1))) void gvoid_t;
typedef __attribute__((address_space(3))) void lvoid_t;

__device__ __forceinline__ void gload16(const void* g, void* l) {
    // width-16 global->LDS DMA; LDS dest is wave-uniform base + lane*16
    __builtin_amdgcn_global_load_lds((gvoid_t*)g, (lvoid_t*)l, 16, 0, 0);
}

// ---------------- pass 0: repack weight int32 -> packed int8 ----------------
// Harness materializes integer inputs as int32; W arrives as [N][K] of int32.
__global__ __launch_bounds__(256)
void repack_w_kernel(const int* __restrict__ wi, int* __restrict__ wq, int n4)
{
    int i = blockIdx.x * blockDim.x + threadIdx.x;
    if (i < n4) {
        v4i v = ((const v4i*)wi)[i];
        wq[i] = (v[0] & 255) | ((v[1] & 255) << 8) |
                ((v[2] & 255) << 16) | ((v[3] & 255) << 24);
    }
}

// ---------------- pass 1: quantize fp32 -> int8 (row-major [M][K]) ----------
__global__ __launch_bounds__(256, 2)
void quant_kernel(const float* __restrict__ x, int* __restrict__ q,
                  const float* __restrict__ iscale_p, int n4)
{
    const float is = *iscale_p;
    int idx = blockIdx.x * blockDim.x + threadIdx.x;
    int stride = gridDim.x * blockDim.x;
    const v4f* xp = (const v4f*)x;
    for (int i = idx; i < n4; i += stride) {
        v4f v = xp[i];
        int r = 0;
        #pragma unroll
        for (int j = 0; j < 4; ++j) {
            float t = rintf(v[j] / is);        // round-half-even, IEEE divide: matches jnp
            t = fminf(127.f, fmaxf(-128.f, t));
            r |= ((int)t & 255) << (8 * j);
        }
        q[i] = r;                               // 4 int8 packed, memory order == x order
    }
}

// ---------------- pass 2: int8 GEMM, C = deq(Aq * W^T) ----------------------
// A: [M][K] int8 (ws), W: [N][K] int8 (ws). 128x128 tile, 4 waves, 16x16x64 i8 MFMA.
__global__ __launch_bounds__(256, 2)
void qgemm_kernel(const signed char* __restrict__ Aq,
                  const signed char* __restrict__ W,
                  const float* __restrict__ wscale,
                  const float* __restrict__ iscale_p,
                  const float* __restrict__ bias,
                  float* __restrict__ out)
{
    __shared__ signed char lA[BM * BKB];
    __shared__ signed char lB[BN * BKB];

    // XCD-aware swizzle (nwg = 2048, divisible by 8): each XCD gets a
    // contiguous chunk of logical tiles -> 8 blocks sharing an A panel
    // co-resident on one XCD's L2.
    const int nwg = gridDim.x;
    const int bid = blockIdx.x;
    const int wg  = (bid & 7) * (nwg >> 3) + (bid >> 3);
    const int m_blk = wg >> 3;                 // N_DIM/BN == 8 col-blocks
    const int n_blk = wg & 7;
    const int mrow0 = m_blk * BM;
    const int ncol0 = n_blk * BN;

    const int tid = threadIdx.x;
    const int wv  = tid >> 6;
    const int ln  = tid & 63;
    const int wm  = wv >> 1;                   // 2x2 wave grid, 64x64 out each
    const int wn  = wv & 1;
    const int lrow = ln & 15;
    const int lk16 = (ln >> 4) << 4;
    const int swz  = (lrow & 7) << 4;          // XOR swizzle key (bits 4-6)

    v4i acc[4][4] = {};

    for (int kt = 0; kt < K_DIM; kt += BKB) {
        __syncthreads();
        // Stage 16KB A + 16KB B. LDS is linear; the global SOURCE is
        // pre-swizzled so that reads with addr^=((row&7)<<4) see the
        // correct element (both-sides-or-neither rule).
        #pragma unroll
        for (int c = 0; c < 4; ++c) {
            const int o   = c * 4096 + wv * 1024 + ln * 16; // linear LDS byte
            const int row = o >> 7;
            const int inr = (o & 127) ^ ((row & 7) << 4);
            gload16(Aq + (size_t)(mrow0 + row) * K_DIM + kt + inr,
                    (void*)(lA + c * 4096 + wv * 1024));
            gload16(W + (size_t)(ncol0 + row) * K_DIM + kt + inr,
                    (void*)(lB + c * 4096 + wv * 1024));
        }
        __syncthreads();
        #pragma unroll
        for (int st = 0; st < 2; ++st) {       // two K=64 steps per tile
            v4i af[4], bf[4];
            #pragma unroll
            for (int i = 0; i < 4; ++i) {
                const int arow = wm * 64 + i * 16 + lrow;
                af[i] = *(const v4i*)&lA[arow * BKB + ((st * 64 + lk16) ^ swz)];
                const int brow = wn * 64 + i * 16 + lrow;
                bf[i] = *(const v4i*)&lB[brow * BKB + ((st * 64 + lk16) ^ swz)];
            }
            #pragma unroll
            for (int i = 0; i < 4; ++i)
                #pragma unroll
                for (int j = 0; j < 4; ++j)
                    acc[i][j] = __builtin_amdgcn_mfma_i32_16x16x64_i8(
                                    af[i], bf[j], acc[i][j], 0, 0, 0);
        }
    }

    // Epilogue: dequant + bias. C/D layout: col = lane&15, row = (lane>>4)*4+r.
    const float is = *iscale_p;
    const int r0 = mrow0 + wm * 64 + ((ln >> 4) << 2);
    const int c0 = ncol0 + wn * 64 + lrow;
    #pragma unroll
    for (int j = 0; j < 4; ++j) {
        const int col = c0 + j * 16;
        const float sc = wscale[col] * is;
        const float bv = bias[col];
        #pragma unroll
        for (int i = 0; i < 4; ++i) {
            const int row = r0 + i * 16;
            #pragma unroll
            for (int r = 0; r < 4; ++r)
                out[(size_t)(row + r) * N_DIM + col] = (float)acc[i][j][r] * sc + bv;
        }
    }
}

extern "C" void kernel_launch(void* const* d_in, const int* in_sizes, int n_in,
                              void* d_out, int out_size, void* d_ws, size_t ws_size,
                              hipStream_t stream)
{
    const float* x       = (const float*)d_in[0];
    const int*   w32     = (const int*)d_in[1];           // int8 weight stored as int32 [N][K]
    const float* wscale  = (const float*)d_in[2];
    const float* iscale  = (const float*)d_in[3];
    const float* bias    = (const float*)d_in[4];
    float* out           = (float*)d_out;

    signed char* aq = (signed char*)d_ws;                 // 32 MiB int8 activations
    signed char* wq = (signed char*)d_ws + (size_t)M_DIM * K_DIM; // +32 MiB: 1 MiB packed W

    const int wn4 = (N_DIM * K_DIM) / 4;                   // 262144
    repack_w_kernel<<<(wn4 + 255) / 256, 256, 0, stream>>>(w32, (int*)wq, wn4);

    quant_kernel<<<8192, 256, 0, stream>>>(x, (int*)aq, iscale, (M_DIM * K_DIM) / 4);

    const int grid = (M_DIM / BM) * (N_DIM / BN);          // 2048 blocks
    qgemm_kernel<<<grid, 256, 0, stream>>>(aq, wq, wscale, iscale, bias, out);
}